// Round 1
// baseline (191.262 us; speedup 1.0000x reference)
//
#include <hip/hip_runtime.h>
#include <hip/hip_bf16.h>

#if defined(__has_builtin)
#if __has_builtin(__builtin_amdgcn_exp2f)
#define EXP2F __builtin_amdgcn_exp2f
#endif
#if __has_builtin(__builtin_amdgcn_rcpf)
#define RCPF __builtin_amdgcn_rcpf
#endif
#endif
#ifndef EXP2F
#define EXP2F exp2f
#endif
#ifndef RCPF
#define RCPF(x) (1.0f / (x))
#endif

// Sizes (fixed by the problem)
#define B_  8
#define Q_  256
#define K_  1024
#define D_  256
#define H_  128
#define DV_ 128

// ---------------------------------------------------------------------------
// Kernel 1: fused projections.
//   blocks 0..31   : qC[row][h]       = (queries @ W_q)[row][h] * 2*log2(e)
//   blocks 32..159 : kTC[b][h][k]     = (keys    @ W_k)[b*K+k][h] * 2*log2(e)
// 64-row x 128-col tile per block, 256 threads, 4x8 micro-tile per thread.
// ---------------------------------------------------------------------------
__global__ __launch_bounds__(256) void proj_kernel(
    const float* __restrict__ queries, const float* __restrict__ keys,
    const float* __restrict__ Wq, const float* __restrict__ Wk,
    float* __restrict__ qC, float* __restrict__ kTC)
{
    __shared__ __align__(16) float As[64][36];   // 64 rows x 32 d (pad->36)
    __shared__ __align__(16) float Ws[32][128];  // 32 d x 128 h

    const int blk = blockIdx.x;
    const bool isQ = blk < 32;
    const float* A = isQ ? queries : keys;
    const float* W = isQ ? Wq : Wk;
    const int row0 = isQ ? blk * 64 : (blk - 32) * 64;
    const int tid = threadIdx.x;

    float acc[4][8];
#pragma unroll
    for (int i = 0; i < 4; i++)
#pragma unroll
        for (int j = 0; j < 8; j++) acc[i][j] = 0.f;

    const int lr = (tid >> 4) * 4;   // local row base 0..60
    const int lc = (tid & 15) * 4;   // local col base; 2nd group at +64

    for (int d0 = 0; d0 < D_; d0 += 32) {
        // stage A tile (64x32)
        {
            const int r = tid >> 3;
            const int c = (tid & 7) * 4;
            float4 a0 = *(const float4*)&A[(row0 + r) * D_ + d0 + c];
            float4 a1 = *(const float4*)&A[(row0 + r + 32) * D_ + d0 + c];
            *(float4*)&As[r][c] = a0;
            *(float4*)&As[r + 32][c] = a1;
        }
        // stage W tile (32x128)
#pragma unroll
        for (int l = 0; l < 4; l++) {
            const int idx = tid + l * 256;
            const int r = idx >> 5;
            const int c = (idx & 31) * 4;
            *(float4*)&Ws[r][c] = *(const float4*)&W[(d0 + r) * H_ + c];
        }
        __syncthreads();
#pragma unroll
        for (int d = 0; d < 32; d++) {
            float a[4], w[8];
#pragma unroll
            for (int i = 0; i < 4; i++) a[i] = As[lr + i][d];
            float4 w0 = *(float4*)&Ws[d][lc];
            float4 w1 = *(float4*)&Ws[d][lc + 64];
            w[0] = w0.x; w[1] = w0.y; w[2] = w0.z; w[3] = w0.w;
            w[4] = w1.x; w[5] = w1.y; w[6] = w1.z; w[7] = w1.w;
#pragma unroll
            for (int i = 0; i < 4; i++)
#pragma unroll
                for (int j = 0; j < 8; j++)
                    acc[i][j] = fmaf(a[i], w[j], acc[i][j]);
        }
        __syncthreads();
    }

    const float CS = 2.8853900817779268f;  // 2*log2(e)
    if (isQ) {
#pragma unroll
        for (int i = 0; i < 4; i++) {
            const int row = row0 + lr + i;
#pragma unroll
            for (int j = 0; j < 8; j++) {
                const int h = (j < 4) ? (lc + j) : (lc + 60 + j);
                qC[row * H_ + h] = acc[i][j] * CS;
            }
        }
    } else {
#pragma unroll
        for (int i = 0; i < 4; i++) {
            const int row = row0 + lr + i;        // = b*K + k
            const int b = row >> 10, k = row & 1023;
#pragma unroll
            for (int j = 0; j < 8; j++) {
                const int h = (j < 4) ? (lc + j) : (lc + 60 + j);
                kTC[b * (H_ * K_) + h * K_ + k] = acc[i][j] * CS;
            }
        }
    }
}

// ---------------------------------------------------------------------------
// Kernel 2: fused scores + masked softmax + AV.
// Block = (b, 4 q-rows). 256 threads.
//   score'(q,k) = sum_h (-2 w_h) * rcp(exp2(qC_h + kTC_hk) + 1)
//   (the constant sum_h w_h cancels under softmax shift-invariance)
// ---------------------------------------------------------------------------
__global__ __launch_bounds__(256) void attn_kernel(
    const float* __restrict__ qC,      // [B*Q][H], pre-scaled by 2log2e
    const float* __restrict__ kTC,     // [B][H][K], pre-scaled by 2log2e
    const float* __restrict__ values,  // [B][K][DV]
    const int*   __restrict__ valid_lens,
    const float* __restrict__ w_v,     // [H]
    float* __restrict__ out)           // [B][Q][DV]
{
    __shared__ float sc[4][K_];
    __shared__ float qs[4][H_];
    __shared__ float wv2[H_];
    __shared__ float rl[4];

    const int tid = threadIdx.x;
    const int b = blockIdx.y;
    const int q0 = blockIdx.x * 4;

    if (tid < H_) wv2[tid] = -2.0f * w_v[tid];
    {
        const float* src = qC + (b * Q_ + q0) * H_;
        ((float*)qs)[tid] = src[tid];
        ((float*)qs)[tid + 256] = src[tid + 256];
    }
    __syncthreads();

    // ---- phase 1: scores ----
    float acc[4][4];
#pragma unroll
    for (int q = 0; q < 4; q++)
#pragma unroll
        for (int j = 0; j < 4; j++) acc[q][j] = 0.f;

    const float* kTb = kTC + b * (H_ * K_) + tid;
#pragma unroll 2
    for (int h = 0; h < H_; h++) {
        float kv[4];
#pragma unroll
        for (int j = 0; j < 4; j++) kv[j] = kTb[h * K_ + j * 256];
        const float wh = wv2[h];
#pragma unroll
        for (int q = 0; q < 4; q++) {
            const float qh = qs[q][h];
#pragma unroll
            for (int j = 0; j < 4; j++) {
                float t = EXP2F(qh + kv[j]);
                float r = RCPF(t + 1.0f);
                acc[q][j] = fmaf(wh, r, acc[q][j]);
            }
        }
    }
    const int vl = valid_lens[b];
#pragma unroll
    for (int q = 0; q < 4; q++)
#pragma unroll
        for (int j = 0; j < 4; j++) {
            const int k = tid + j * 256;
            sc[q][k] = (k < vl) ? acc[q][j] : -1e6f;
        }
    __syncthreads();

    // ---- phase 2: masked softmax (wave w handles q=w), unnormalized ----
    {
        const int q = tid >> 6, lane = tid & 63;
        float v[16];
        float m = -3.0e38f;
#pragma unroll
        for (int i = 0; i < 16; i++) {
            v[i] = sc[q][lane + i * 64];
            m = fmaxf(m, v[i]);
        }
#pragma unroll
        for (int s = 32; s > 0; s >>= 1) m = fmaxf(m, __shfl_xor(m, s));
        const float L2E = 1.4426950408889634f;
        const float mm = m * L2E;
        float l = 0.f;
#pragma unroll
        for (int i = 0; i < 16; i++) {
            float e = EXP2F(fmaf(v[i], L2E, -mm));
            sc[q][lane + i * 64] = e;
            l += e;
        }
#pragma unroll
        for (int s = 32; s > 0; s >>= 1) l += __shfl_xor(l, s);
        if (lane == 0) rl[q] = RCPF(l);
    }
    __syncthreads();

    // ---- phase 3: AV ----
    {
        const int v = tid & 127;
        const int qh = tid >> 7;  // 0/1; thread does q = qh and qh+2
        const float* vb = values + b * (K_ * DV_) + v;
        float a0 = 0.f, a1 = 0.f;
#pragma unroll 8
        for (int k = 0; k < K_; k++) {
            const float val = vb[k * DV_];
            a0 = fmaf(sc[qh][k], val, a0);
            a1 = fmaf(sc[qh + 2][k], val, a1);
        }
        float* ob = out + (b * Q_ + q0) * DV_ + v;
        ob[qh * DV_] = a0 * rl[qh];
        ob[(qh + 2) * DV_] = a1 * rl[qh + 2];
    }
}

extern "C" void kernel_launch(void* const* d_in, const int* in_sizes, int n_in,
                              void* d_out, int out_size, void* d_ws, size_t ws_size,
                              hipStream_t stream) {
    const float* queries    = (const float*)d_in[0];  // [8,256,256]
    const float* keys       = (const float*)d_in[1];  // [8,1024,256]
    const float* values     = (const float*)d_in[2];  // [8,1024,128]
    const int*   valid_lens = (const int*)d_in[3];    // [8]
    const float* W_q        = (const float*)d_in[4];  // [256,128]
    const float* W_k        = (const float*)d_in[5];  // [256,128]
    const float* w_v        = (const float*)d_in[6];  // [128]
    float* out = (float*)d_out;

    float* qC  = (float*)d_ws;                  // B*Q*H  = 262144 floats (1 MB)
    float* kTC = qC + (B_ * Q_ * H_);           // B*H*K  = 1048576 floats (4 MB)

    // 32 blocks for q-proj (2048 rows), 128 blocks for k-proj (8192 rows)
    proj_kernel<<<160, 256, 0, stream>>>(queries, keys, W_q, W_k, qC, kTC);
    attn_kernel<<<dim3(Q_ / 4, B_), 256, 0, stream>>>(qC, kTC, values, valid_lens, w_v, out);
}

// Round 2
// 145.848 us; speedup vs baseline: 1.3114x; 1.3114x over previous
//
#include <hip/hip_runtime.h>
#include <hip/hip_bf16.h>

#if defined(__has_builtin)
#if __has_builtin(__builtin_amdgcn_exp2f)
#define EXP2F __builtin_amdgcn_exp2f
#endif
#if __has_builtin(__builtin_amdgcn_rcpf)
#define RCPF __builtin_amdgcn_rcpf
#endif
#endif
#ifndef EXP2F
#define EXP2F exp2f
#endif
#ifndef RCPF
#define RCPF(x) (1.0f / (x))
#endif

// Sizes (fixed by the problem)
#define B_  8
#define Q_  256
#define K_  1024
#define D_  256
#define H_  128
#define DV_ 128

#define CSL 2.8853900817779268f   // 2*log2(e)
#define L2E 1.4426950408889634f   // log2(e)

// ---------------------------------------------------------------------------
// Kernel 1: projections, storing EXPONENTIATED results.
//   blocks 0..127  : qE[row][h]   = exp2(CSL * (queries @ W_q)[row][h]) = e^{2q}
//   blocks 128..639: kE[b][h][k]  = exp2(CSL * (keys    @ W_k)[row][h]) = e^{2k}
// 16-row x 128-col tile per block (640 blocks -> 2.5 blocks/CU).
// ---------------------------------------------------------------------------
__global__ __launch_bounds__(256) void proj_kernel(
    const float* __restrict__ queries, const float* __restrict__ keys,
    const float* __restrict__ Wq, const float* __restrict__ Wk,
    float* __restrict__ qE, float* __restrict__ kE)
{
    __shared__ __align__(16) float As[16][36];   // 16 rows x 32 d (pad->36)
    __shared__ __align__(16) float Ws[32][128];  // 32 d x 128 h

    const int tid = threadIdx.x;
    const int blk = blockIdx.x;
    const bool isQ = blk < 128;                  // 128*16 = 2048 q rows
    const int row0 = isQ ? blk * 16 : (blk - 128) * 16;
    const float* A = isQ ? (queries + row0 * D_) : (keys + row0 * D_);
    const float* W = isQ ? Wq : Wk;

    float acc[8];
#pragma unroll
    for (int j = 0; j < 8; j++) acc[j] = 0.f;

    const int r  = tid >> 4;        // 0..15 (local row)
    const int c8 = (tid & 15) * 8;  // 0..120 (h base)

    for (int d0 = 0; d0 < D_; d0 += 32) {
        if (tid < 128) {
            const int rr = tid >> 3, cc = (tid & 7) * 4;
            *(float4*)&As[rr][cc] = *(const float4*)&A[rr * D_ + d0 + cc];
        }
#pragma unroll
        for (int l = 0; l < 4; l++) {
            const int idx = tid + l * 256;
            const int rr = idx >> 5, cc = (idx & 31) * 4;
            *(float4*)&Ws[rr][cc] = *(const float4*)&W[(d0 + rr) * H_ + cc];
        }
        __syncthreads();
#pragma unroll
        for (int d = 0; d < 32; d++) {
            const float a = As[r][d];
            const float4 w0 = *(const float4*)&Ws[d][c8];
            const float4 w1 = *(const float4*)&Ws[d][c8 + 4];
            acc[0] = fmaf(a, w0.x, acc[0]);
            acc[1] = fmaf(a, w0.y, acc[1]);
            acc[2] = fmaf(a, w0.z, acc[2]);
            acc[3] = fmaf(a, w0.w, acc[3]);
            acc[4] = fmaf(a, w1.x, acc[4]);
            acc[5] = fmaf(a, w1.y, acc[5]);
            acc[6] = fmaf(a, w1.z, acc[6]);
            acc[7] = fmaf(a, w1.w, acc[7]);
        }
        __syncthreads();
    }

    float e[8];
#pragma unroll
    for (int j = 0; j < 8; j++) e[j] = EXP2F(CSL * acc[j]);

    if (isQ) {
        float* dst = qE + (row0 + r) * H_ + c8;
        *(float4*)dst = make_float4(e[0], e[1], e[2], e[3]);
        *(float4*)(dst + 4) = make_float4(e[4], e[5], e[6], e[7]);
    } else {
        const int krow = row0 + r;                 // global key row
        const int b = krow >> 10, k = krow & 1023; // 16-row tiles never cross b
        float* dst = kE + b * (H_ * K_) + c8 * K_ + k;
#pragma unroll
        for (int j = 0; j < 8; j++) dst[j * K_] = e[j];
    }
}

// ---------------------------------------------------------------------------
// Kernel 2: scores + (no-max) masked softmax + AV. 512 threads, 4 q-rows/block.
//   acc(q,k) = sum_h (-2*log2e*w_h) / (Eq_h * Ek_hk + 1)   [log2-domain score]
//   p = exp2(acc) (masked -> 0);  out = (P @ V) / sum_k p
// Bound |score| <= 2*sum|w_h| ~ 18  ->  no max-subtraction needed.
// ---------------------------------------------------------------------------
__global__ __launch_bounds__(512) void attn_kernel(
    const float* __restrict__ qE,      // [B*Q][H] = e^{2q}
    const float* __restrict__ kE,      // [B][H][K] = e^{2k}
    const float* __restrict__ values,  // [B][K][DV]
    const int*   __restrict__ valid_lens,
    const float* __restrict__ w_v,     // [H]
    float* __restrict__ out)           // [B][Q][DV]
{
    __shared__ __align__(16) float sc[K_][4];        // 16 KB  p-values
    __shared__ __align__(16) float qs[H_][4];        // 2 KB   Eq, [h][q]
    __shared__ float wv2[H_];
    __shared__ __align__(16) float psum[8][4];       // per-wave partial sums
    __shared__ float rl[4];
    __shared__ __align__(16) float red[16][4][128];  // 32 KB AV reduction

    const int tid = threadIdx.x;
    const int b  = blockIdx.y;
    const int q0 = blockIdx.x * 4;

    if (tid < H_) wv2[tid] = -2.0f * L2E * w_v[tid];
    {
        const float* src = qE + (b * Q_ + q0) * H_;
        const int h = tid & 127, q = tid >> 7;       // q = 0..3
        qs[h][q] = src[q * H_ + h];
    }
    __syncthreads();

    // ---- phase 1: log2-domain scores, 2 k per thread ----
    float a0x = 0.f, a0y = 0.f, a1x = 0.f, a1y = 0.f;
    float a2x = 0.f, a2y = 0.f, a3x = 0.f, a3y = 0.f;
    const int k0 = tid * 2;
    const float* kb = kE + b * (H_ * K_) + k0;
#pragma unroll 4
    for (int h = 0; h < H_; h++) {
        const float2 ek = *(const float2*)(kb + h * K_);
        const float4 qv = *(const float4*)&qs[h][0];
        const float wh = wv2[h];
        float t, r;
        t = fmaf(qv.x, ek.x, 1.0f); r = RCPF(t); a0x = fmaf(wh, r, a0x);
        t = fmaf(qv.x, ek.y, 1.0f); r = RCPF(t); a0y = fmaf(wh, r, a0y);
        t = fmaf(qv.y, ek.x, 1.0f); r = RCPF(t); a1x = fmaf(wh, r, a1x);
        t = fmaf(qv.y, ek.y, 1.0f); r = RCPF(t); a1y = fmaf(wh, r, a1y);
        t = fmaf(qv.z, ek.x, 1.0f); r = RCPF(t); a2x = fmaf(wh, r, a2x);
        t = fmaf(qv.z, ek.y, 1.0f); r = RCPF(t); a2y = fmaf(wh, r, a2y);
        t = fmaf(qv.w, ek.x, 1.0f); r = RCPF(t); a3x = fmaf(wh, r, a3x);
        t = fmaf(qv.w, ek.y, 1.0f); r = RCPF(t); a3y = fmaf(wh, r, a3y);
    }

    // ---- phase 2: exp (no max needed) + mask + row-sum ----
    const int vl = valid_lens[b];
    float p0x = (k0     < vl) ? EXP2F(a0x) : 0.f;
    float p0y = (k0 + 1 < vl) ? EXP2F(a0y) : 0.f;
    float p1x = (k0     < vl) ? EXP2F(a1x) : 0.f;
    float p1y = (k0 + 1 < vl) ? EXP2F(a1y) : 0.f;
    float p2x = (k0     < vl) ? EXP2F(a2x) : 0.f;
    float p2y = (k0 + 1 < vl) ? EXP2F(a2y) : 0.f;
    float p3x = (k0     < vl) ? EXP2F(a3x) : 0.f;
    float p3y = (k0 + 1 < vl) ? EXP2F(a3y) : 0.f;
    *(float4*)&sc[k0][0]     = make_float4(p0x, p1x, p2x, p3x);
    *(float4*)&sc[k0 + 1][0] = make_float4(p0y, p1y, p2y, p3y);

    float ps[4] = {p0x + p0y, p1x + p1y, p2x + p2y, p3x + p3y};
#pragma unroll
    for (int s = 32; s > 0; s >>= 1) {
#pragma unroll
        for (int q = 0; q < 4; q++) ps[q] += __shfl_xor(ps[q], s);
    }
    const int lane = tid & 63, w = tid >> 6;
    if (lane == 0) *(float4*)&psum[w][0] = make_float4(ps[0], ps[1], ps[2], ps[3]);
    __syncthreads();
    if (tid < 4) {
        float s = 0.f;
#pragma unroll
        for (int ww = 0; ww < 8; ww++) s += psum[ww][tid];
        rl[tid] = RCPF(s);
    }

    // ---- phase 3: AV, k-split into 16 chunks, float4 value loads ----
    {
        const int v4 = (tid & 31) * 4;
        const int kc = tid >> 5;                    // 0..15
        const float* vb = values + b * (K_ * DV_) + v4;
        float av[4][4];
#pragma unroll
        for (int q = 0; q < 4; q++)
#pragma unroll
            for (int j = 0; j < 4; j++) av[q][j] = 0.f;
#pragma unroll 2
        for (int kk = 0; kk < 64; kk++) {
            const int k = kc * 64 + kk;
            const float4 vv = *(const float4*)&vb[k * DV_];
            const float4 p  = *(const float4*)&sc[k][0];
            av[0][0] = fmaf(p.x, vv.x, av[0][0]);
            av[0][1] = fmaf(p.x, vv.y, av[0][1]);
            av[0][2] = fmaf(p.x, vv.z, av[0][2]);
            av[0][3] = fmaf(p.x, vv.w, av[0][3]);
            av[1][0] = fmaf(p.y, vv.x, av[1][0]);
            av[1][1] = fmaf(p.y, vv.y, av[1][1]);
            av[1][2] = fmaf(p.y, vv.z, av[1][2]);
            av[1][3] = fmaf(p.y, vv.w, av[1][3]);
            av[2][0] = fmaf(p.z, vv.x, av[2][0]);
            av[2][1] = fmaf(p.z, vv.y, av[2][1]);
            av[2][2] = fmaf(p.z, vv.z, av[2][2]);
            av[2][3] = fmaf(p.z, vv.w, av[2][3]);
            av[3][0] = fmaf(p.w, vv.x, av[3][0]);
            av[3][1] = fmaf(p.w, vv.y, av[3][1]);
            av[3][2] = fmaf(p.w, vv.z, av[3][2]);
            av[3][3] = fmaf(p.w, vv.w, av[3][3]);
        }
#pragma unroll
        for (int q = 0; q < 4; q++)
            *(float4*)&red[kc][q][v4] =
                make_float4(av[q][0], av[q][1], av[q][2], av[q][3]);
    }
    __syncthreads();

    // ---- final: reduce 16 chunks, normalize, store ----
    {
        const int q = tid >> 7, v = tid & 127;
        float s = 0.f;
#pragma unroll
        for (int g = 0; g < 16; g++) s += red[g][q][v];
        out[(b * Q_ + q0 + q) * DV_ + v] = s * rl[q];
    }
}

extern "C" void kernel_launch(void* const* d_in, const int* in_sizes, int n_in,
                              void* d_out, int out_size, void* d_ws, size_t ws_size,
                              hipStream_t stream) {
    const float* queries    = (const float*)d_in[0];  // [8,256,256]
    const float* keys       = (const float*)d_in[1];  // [8,1024,256]
    const float* values     = (const float*)d_in[2];  // [8,1024,128]
    const int*   valid_lens = (const int*)d_in[3];    // [8]
    const float* W_q        = (const float*)d_in[4];  // [256,128]
    const float* W_k        = (const float*)d_in[5];  // [256,128]
    const float* w_v        = (const float*)d_in[6];  // [128]
    float* out = (float*)d_out;

    float* qE = (float*)d_ws;               // B*Q*H = 262144 floats (1 MB)
    float* kE = qE + (B_ * Q_ * H_);        // B*H*K = 1048576 floats (4 MB)

    proj_kernel<<<640, 256, 0, stream>>>(queries, keys, W_q, W_k, qE, kE);
    attn_kernel<<<dim3(Q_ / 4, B_), 512, 0, stream>>>(qE, kE, values, valid_lens, w_v, out);
}

// Round 4
// 140.100 us; speedup vs baseline: 1.3652x; 1.0410x over previous
//
#include <hip/hip_runtime.h>
#include <hip/hip_bf16.h>

#if defined(__has_builtin)
#if __has_builtin(__builtin_amdgcn_exp2f)
#define EXP2F __builtin_amdgcn_exp2f
#endif
#if __has_builtin(__builtin_amdgcn_rcpf)
#define RCPF __builtin_amdgcn_rcpf
#endif
#endif
#ifndef EXP2F
#define EXP2F exp2f
#endif
#ifndef RCPF
#define RCPF(x) (1.0f / (x))
#endif

// Sizes (fixed by the problem)
#define B_  8
#define Q_  256
#define K_  1024
#define D_  256
#define H_  128
#define DV_ 128

#define CSL 2.8853900817779268f   // 2*log2(e)
#define L2E 1.4426950408889634f   // log2(e)

// Workspace layout (in floats)
#define QE_OFF   0                // qE  [B*Q][H]        = 262144
#define KE_OFF   262144           // kET [B][H][K]       = 1048576
#define WPK_OFF  1310720          // wpk [64] float4     = 256
#define PART_OFF 1311744          // partials, S x PSZ
#define PSZ      1310720          // 10240*128 (concat rows: q 0..2047, k 2048..10239)

// ---------------------------------------------------------------------------
// proj_split: raw projections with split-K. Tile 64 rows x 128 cols per block,
// 256 threads, 8x4 thread tile. blockIdx.y = d-chunk group (nchunk*64 d each).
// Writes fp32 partial sums to part[blockIdx.y] at the CONCATENATED row index
// (k rows offset by +2048 — this was the round-3 bug).
// ---------------------------------------------------------------------------
__global__ __launch_bounds__(256) void proj_split(
    const float* __restrict__ queries, const float* __restrict__ keys,
    const float* __restrict__ Wq, const float* __restrict__ Wk,
    float* __restrict__ part, int nchunk)
{
    __shared__ __align__(16) float As[64][68];   // [d][row], pad 68
    __shared__ __align__(16) float Ws[64][128];  // [d][col]

    const int tid = threadIdx.x;
    const int rt = blockIdx.x;                  // 0..159
    const bool isQ = rt < 32;
    const int row0 = isQ ? rt * 64 : (rt - 32) * 64;   // row within q or k block
    const int crow0 = isQ ? row0 : row0 + 2048;        // concatenated row base
    const float* A = isQ ? (queries + row0 * D_) : (keys + row0 * D_);
    const float* W = isQ ? Wq : Wk;

    float acc[8][4];
#pragma unroll
    for (int i = 0; i < 8; i++)
#pragma unroll
        for (int j = 0; j < 4; j++) acc[i][j] = 0.f;

    const int rgrp = tid >> 5;          // 0..7 -> rows rgrp*8..+7
    const int c0 = (tid & 31) * 4;      // col base
    const int lr = tid & 63;            // A-load row
    const int ld = (tid >> 6) * 16;     // A-load d base

    for (int ch = 0; ch < nchunk; ch++) {
        const int d0 = (blockIdx.y * nchunk + ch) * 64;
        // stage A transposed: As[d][r]
#pragma unroll
        for (int j = 0; j < 4; j++) {
            const float4 a = *(const float4*)&A[lr * D_ + d0 + ld + j * 4];
            As[ld + j * 4 + 0][lr] = a.x;
            As[ld + j * 4 + 1][lr] = a.y;
            As[ld + j * 4 + 2][lr] = a.z;
            As[ld + j * 4 + 3][lr] = a.w;
        }
        // stage W: 64x128
#pragma unroll
        for (int l = 0; l < 8; l++) {
            const int idx = tid + l * 256;
            const int rr = idx >> 5, cc = (idx & 31) * 4;
            *(float4*)&Ws[rr][cc] = *(const float4*)&W[(d0 + rr) * H_ + cc];
        }
        __syncthreads();
#pragma unroll 4
        for (int d = 0; d < 64; d++) {
            const float4 w = *(const float4*)&Ws[d][c0];
            const float4 a0 = *(const float4*)&As[d][rgrp * 8];
            const float4 a1 = *(const float4*)&As[d][rgrp * 8 + 4];
            const float ar[8] = {a0.x, a0.y, a0.z, a0.w, a1.x, a1.y, a1.z, a1.w};
#pragma unroll
            for (int i = 0; i < 8; i++) {
                acc[i][0] = fmaf(ar[i], w.x, acc[i][0]);
                acc[i][1] = fmaf(ar[i], w.y, acc[i][1]);
                acc[i][2] = fmaf(ar[i], w.z, acc[i][2]);
                acc[i][3] = fmaf(ar[i], w.w, acc[i][3]);
            }
        }
        __syncthreads();
    }
    float* dst = part + (size_t)blockIdx.y * PSZ + (size_t)(crow0 + rgrp * 8) * H_ + c0;
#pragma unroll
    for (int i = 0; i < 8; i++)
        *(float4*)&dst[i * H_] = make_float4(acc[i][0], acc[i][1], acc[i][2], acc[i][3]);
}

// ---------------------------------------------------------------------------
// finish_kernel: sum S partials, exp2(CSL*x); q-rows -> qE direct; k-rows ->
// LDS transpose -> kET[b][h][k]. Block = 32 rows x 128 h. Also writes wpk.
// ---------------------------------------------------------------------------
__global__ __launch_bounds__(256) void finish_kernel(
    const float* __restrict__ part, int S,
    const float* __restrict__ w_v,
    float* __restrict__ qE, float* __restrict__ kET, float* __restrict__ wpk)
{
    __shared__ float T[128][33];
    const int tid = threadIdx.x;
    const int row0 = blockIdx.x * 32;          // concatenated row base
    const bool isQ = row0 < 2048;

    float e[16];
#pragma unroll
    for (int i = 0; i < 16; i++) {
        const int idx = row0 * H_ + tid + i * 256;
        float v = part[idx];
        for (int s = 1; s < S; s++) v += part[(size_t)s * PSZ + idx];
        e[i] = EXP2F(CSL * v);
    }
    if (isQ) {
#pragma unroll
        for (int i = 0; i < 16; i++) qE[row0 * H_ + tid + i * 256] = e[i];
    } else {
#pragma unroll
        for (int i = 0; i < 16; i++) {
            const int idx = tid + i * 256;
            T[idx & 127][idx >> 7] = e[i];
        }
        __syncthreads();
        const int krow0 = row0 - 2048;
        const int b = krow0 >> 10, k0 = krow0 & 1023;
        const int h = tid >> 1, kh = (tid & 1) * 16;
        float* dst = kET + (size_t)b * (H_ * K_) + (size_t)h * K_ + k0 + kh;
#pragma unroll
        for (int j = 0; j < 4; j++)
            *(float4*)&dst[j * 4] = make_float4(T[h][kh + j * 4], T[h][kh + j * 4 + 1],
                                                T[h][kh + j * 4 + 2], T[h][kh + j * 4 + 3]);
    }
    if (blockIdx.x == 0 && tid < 64) {
        const float w1 = -2.0f * L2E * w_v[2 * tid];
        const float w2 = -2.0f * L2E * w_v[2 * tid + 1];
        *(float4*)&wpk[tid * 4] = make_float4(w1, w2, w1 + w2, 0.f);
    }
}

// Tiny wpk writer for the fallback path.
__global__ void wpk_kernel(const float* __restrict__ w_v, float* __restrict__ wpk) {
    const int t = threadIdx.x;
    const float w1 = -2.0f * L2E * w_v[2 * t];
    const float w2 = -2.0f * L2E * w_v[2 * t + 1];
    *(float4*)&wpk[t * 4] = make_float4(w1, w2, w1 + w2, 0.f);
}

// ---------------------------------------------------------------------------
// proj_direct: fallback (round-2 style) if ws is too small for split-K.
// ---------------------------------------------------------------------------
__global__ __launch_bounds__(256) void proj_direct(
    const float* __restrict__ queries, const float* __restrict__ keys,
    const float* __restrict__ Wq, const float* __restrict__ Wk,
    float* __restrict__ qE, float* __restrict__ kE)
{
    __shared__ __align__(16) float As[16][36];
    __shared__ __align__(16) float Ws[32][128];

    const int tid = threadIdx.x;
    const int blk = blockIdx.x;
    const bool isQ = blk < 128;
    const int row0 = isQ ? blk * 16 : (blk - 128) * 16;
    const float* A = isQ ? (queries + row0 * D_) : (keys + row0 * D_);
    const float* W = isQ ? Wq : Wk;

    float acc[8];
#pragma unroll
    for (int j = 0; j < 8; j++) acc[j] = 0.f;
    const int r = tid >> 4;
    const int c8 = (tid & 15) * 8;

    for (int d0 = 0; d0 < D_; d0 += 32) {
        if (tid < 128) {
            const int rr = tid >> 3, cc = (tid & 7) * 4;
            *(float4*)&As[rr][cc] = *(const float4*)&A[rr * D_ + d0 + cc];
        }
#pragma unroll
        for (int l = 0; l < 4; l++) {
            const int idx = tid + l * 256;
            const int rr = idx >> 5, cc = (idx & 31) * 4;
            *(float4*)&Ws[rr][cc] = *(const float4*)&W[(d0 + rr) * H_ + cc];
        }
        __syncthreads();
#pragma unroll
        for (int d = 0; d < 32; d++) {
            const float a = As[r][d];
            const float4 w0 = *(const float4*)&Ws[d][c8];
            const float4 w1 = *(const float4*)&Ws[d][c8 + 4];
            acc[0] = fmaf(a, w0.x, acc[0]); acc[1] = fmaf(a, w0.y, acc[1]);
            acc[2] = fmaf(a, w0.z, acc[2]); acc[3] = fmaf(a, w0.w, acc[3]);
            acc[4] = fmaf(a, w1.x, acc[4]); acc[5] = fmaf(a, w1.y, acc[5]);
            acc[6] = fmaf(a, w1.z, acc[6]); acc[7] = fmaf(a, w1.w, acc[7]);
        }
        __syncthreads();
    }
    float e[8];
#pragma unroll
    for (int j = 0; j < 8; j++) e[j] = EXP2F(CSL * acc[j]);
    if (isQ) {
        float* dst = qE + (row0 + r) * H_ + c8;
        *(float4*)dst = make_float4(e[0], e[1], e[2], e[3]);
        *(float4*)(dst + 4) = make_float4(e[4], e[5], e[6], e[7]);
    } else {
        const int krow = row0 + r;
        const int b = krow >> 10, k = krow & 1023;
        float* dst = kE + b * (H_ * K_) + c8 * K_ + k;
#pragma unroll
        for (int j = 0; j < 8; j++) dst[j * K_] = e[j];
    }
}

// ---------------------------------------------------------------------------
// attn_kernel: 1024 threads, 1 k per thread, 4 q-rows per block.
// Phase 1 uses only scalar (wave-uniform) q/w loads + coalesced kET loads.
// h-pairing: w1/(1+x1)+w2/(1+x2) = [(w1+w2)+w1*x2+w2*x1]/[(1+x1)(1+x2)]
//   -> one rcp per two h's. acc is the log2-domain score; p = exp2(acc).
// ---------------------------------------------------------------------------
__global__ __launch_bounds__(1024, 8) void attn_kernel(
    const float* __restrict__ qE,      // [B*Q][H] = e^{2q}
    const float* __restrict__ kET,     // [B][H][K] = e^{2k}
    const float* __restrict__ values,  // [B][K][DV]
    const int*   __restrict__ valid_lens,
    const float* __restrict__ wpk,     // [64] float4 (w1,w2,w1+w2,0), w=-2*log2e*w_v
    float* __restrict__ out)           // [B][Q][DV]
{
    __shared__ __align__(16) float sc[K_][4];        // 16 KB p-values
    __shared__ __align__(16) float red[16][4][128];  // 32 KB AV reduction
    __shared__ __align__(16) float psum[16][4];
    __shared__ float rl[4];

    const int tid = threadIdx.x;
    const int b  = blockIdx.y;
    const int q0 = blockIdx.x * 4;

    const float* q0p = qE + (b * Q_ + q0) * H_;
    const float* q1p = q0p + H_;
    const float* q2p = q0p + 2 * H_;
    const float* q3p = q0p + 3 * H_;
    const float* kb = kET + (size_t)b * (H_ * K_) + tid;

    float2 acc01 = make_float2(0.f, 0.f);
    float2 acc23 = make_float2(0.f, 0.f);

#pragma unroll 4
    for (int p = 0; p < 64; p++) {
        const float ek1 = kb[(2 * p) * K_];
        const float ek2 = kb[(2 * p + 1) * K_];
        const float4 wp = *(const float4*)&wpk[p * 4];
        const float2 qa = *(const float2*)&q0p[2 * p];
        const float2 qb = *(const float2*)&q1p[2 * p];
        const float2 qc = *(const float2*)&q2p[2 * p];
        const float2 qd = *(const float2*)&q3p[2 * p];
        {   // q rows 0,1 packed
            float2 x1 = make_float2(qa.x * ek1, qb.x * ek1);
            float2 x2 = make_float2(qa.y * ek2, qb.y * ek2);
            float2 e1 = make_float2(x1.x + 1.f, x1.y + 1.f);
            float2 d  = make_float2(fmaf(e1.x, x2.x, e1.x), fmaf(e1.y, x2.y, e1.y));
            float2 n  = make_float2(fmaf(wp.y, x1.x, wp.z), fmaf(wp.y, x1.y, wp.z));
            n = make_float2(fmaf(wp.x, x2.x, n.x), fmaf(wp.x, x2.y, n.y));
            acc01.x = fmaf(n.x, RCPF(d.x), acc01.x);
            acc01.y = fmaf(n.y, RCPF(d.y), acc01.y);
        }
        {   // q rows 2,3 packed
            float2 x1 = make_float2(qc.x * ek1, qd.x * ek1);
            float2 x2 = make_float2(qc.y * ek2, qd.y * ek2);
            float2 e1 = make_float2(x1.x + 1.f, x1.y + 1.f);
            float2 d  = make_float2(fmaf(e1.x, x2.x, e1.x), fmaf(e1.y, x2.y, e1.y));
            float2 n  = make_float2(fmaf(wp.y, x1.x, wp.z), fmaf(wp.y, x1.y, wp.z));
            n = make_float2(fmaf(wp.x, x2.x, n.x), fmaf(wp.x, x2.y, n.y));
            acc23.x = fmaf(n.x, RCPF(d.x), acc23.x);
            acc23.y = fmaf(n.y, RCPF(d.y), acc23.y);
        }
    }

    // ---- exp + mask + row sums (k = tid) ----
    const int vl = valid_lens[b];
    const bool valid = tid < vl;
    float4 pv;
    pv.x = valid ? EXP2F(acc01.x) : 0.f;
    pv.y = valid ? EXP2F(acc01.y) : 0.f;
    pv.z = valid ? EXP2F(acc23.x) : 0.f;
    pv.w = valid ? EXP2F(acc23.y) : 0.f;
    *(float4*)&sc[tid][0] = pv;

    float4 s = pv;
#pragma unroll
    for (int sh = 32; sh > 0; sh >>= 1) {
        s.x += __shfl_xor(s.x, sh);
        s.y += __shfl_xor(s.y, sh);
        s.z += __shfl_xor(s.z, sh);
        s.w += __shfl_xor(s.w, sh);
    }
    const int lane = tid & 63, w = tid >> 6;
    if (lane == 0) *(float4*)&psum[w][0] = s;
    __syncthreads();
    if (tid < 4) {
        float t = 0.f;
#pragma unroll
        for (int ww = 0; ww < 16; ww++) t += psum[ww][tid];
        rl[tid] = RCPF(t);
    }

    // ---- AV: thread = (kc 0..15, kh 0..1, vg 0..31), 32 k-iters ----
    const int vg = (tid & 31) * 4;
    const int kh = (tid >> 5) & 1;
    const int kc = tid >> 6;
    const float* vb = values + (size_t)b * (K_ * DV_) + vg;
    float av[4][4];
#pragma unroll
    for (int q = 0; q < 4; q++)
#pragma unroll
        for (int j = 0; j < 4; j++) av[q][j] = 0.f;
#pragma unroll 2
    for (int i = 0; i < 32; i++) {
        const int k = kc * 64 + i * 2 + kh;
        const float4 vv = *(const float4*)&vb[k * DV_];
        const float4 p = *(const float4*)&sc[k][0];
        av[0][0] = fmaf(p.x, vv.x, av[0][0]); av[0][1] = fmaf(p.x, vv.y, av[0][1]);
        av[0][2] = fmaf(p.x, vv.z, av[0][2]); av[0][3] = fmaf(p.x, vv.w, av[0][3]);
        av[1][0] = fmaf(p.y, vv.x, av[1][0]); av[1][1] = fmaf(p.y, vv.y, av[1][1]);
        av[1][2] = fmaf(p.y, vv.z, av[1][2]); av[1][3] = fmaf(p.y, vv.w, av[1][3]);
        av[2][0] = fmaf(p.z, vv.x, av[2][0]); av[2][1] = fmaf(p.z, vv.y, av[2][1]);
        av[2][2] = fmaf(p.z, vv.z, av[2][2]); av[2][3] = fmaf(p.z, vv.w, av[2][3]);
        av[3][0] = fmaf(p.w, vv.x, av[3][0]); av[3][1] = fmaf(p.w, vv.y, av[3][1]);
        av[3][2] = fmaf(p.w, vv.z, av[3][2]); av[3][3] = fmaf(p.w, vv.w, av[3][3]);
    }
    // fold kh pairs (threads tid and tid^32 hold same (kc,vg))
#pragma unroll
    for (int q = 0; q < 4; q++)
#pragma unroll
        for (int j = 0; j < 4; j++) av[q][j] += __shfl_xor(av[q][j], 32);
    if (kh == 0) {
#pragma unroll
        for (int q = 0; q < 4; q++)
            *(float4*)&red[kc][q][vg] = make_float4(av[q][0], av[q][1], av[q][2], av[q][3]);
    }
    __syncthreads();

    if (tid < 512) {
        const int q = tid >> 7, v = tid & 127;
        float t = 0.f;
#pragma unroll
        for (int g = 0; g < 16; g++) t += red[g][q][v];
        out[(b * Q_ + q0 + q) * DV_ + v] = t * rl[q];
    }
}

extern "C" void kernel_launch(void* const* d_in, const int* in_sizes, int n_in,
                              void* d_out, int out_size, void* d_ws, size_t ws_size,
                              hipStream_t stream) {
    const float* queries    = (const float*)d_in[0];  // [8,256,256]
    const float* keys       = (const float*)d_in[1];  // [8,1024,256]
    const float* values     = (const float*)d_in[2];  // [8,1024,128]
    const int*   valid_lens = (const int*)d_in[3];    // [8]
    const float* W_q        = (const float*)d_in[4];  // [256,128]
    const float* W_k        = (const float*)d_in[5];  // [256,128]
    const float* w_v        = (const float*)d_in[6];  // [128]
    float* out = (float*)d_out;

    float* ws  = (float*)d_ws;
    float* qE  = ws + QE_OFF;
    float* kET = ws + KE_OFF;
    float* wpk = ws + WPK_OFF;
    float* part = ws + PART_OFF;

    int S = 0;
    if (ws_size >= (size_t)(PART_OFF + 4 * (size_t)PSZ) * 4) S = 4;
    else if (ws_size >= (size_t)(PART_OFF + 2 * (size_t)PSZ) * 4) S = 2;
    else if (ws_size >= (size_t)(PART_OFF + 1 * (size_t)PSZ) * 4) S = 1;

    if (S > 0) {
        proj_split<<<dim3(160, S), 256, 0, stream>>>(queries, keys, W_q, W_k, part, 4 / S);
        finish_kernel<<<320, 256, 0, stream>>>(part, S, w_v, qE, kET, wpk);
    } else {
        proj_direct<<<640, 256, 0, stream>>>(queries, keys, W_q, W_k, qE, kET);
        wpk_kernel<<<1, 64, 0, stream>>>(w_v, wpk);
    }
    attn_kernel<<<dim3(Q_ / 4, B_), 1024, 0, stream>>>(qE, kET, values, valid_lens, wpk, out);
}

// Round 5
// 121.383 us; speedup vs baseline: 1.5757x; 1.1542x over previous
//
#include <hip/hip_runtime.h>
#include <hip/hip_bf16.h>

#if defined(__has_builtin)
#if __has_builtin(__builtin_amdgcn_exp2f)
#define EXP2F __builtin_amdgcn_exp2f
#endif
#if __has_builtin(__builtin_amdgcn_rcpf)
#define RCPF __builtin_amdgcn_rcpf
#endif
#endif
#ifndef EXP2F
#define EXP2F exp2f
#endif
#ifndef RCPF
#define RCPF(x) (1.0f / (x))
#endif

// Sizes (fixed by the problem)
#define B_  8
#define Q_  256
#define K_  1024
#define D_  256
#define H_  128
#define DV_ 128

#define CSL 2.8853900817779268f   // 2*log2(e)
#define L2E 1.4426950408889634f   // log2(e)

// Workspace layout (floats). Total ~5.25 MB (known-safe from rounds 2/4).
#define QE_OFF   0                // qE   [B*Q][H]              = 262144
#define KE_OFF   262144           // kET2 [B][64 p][K] float2   = 1048576 floats
#define WPK_OFF  1310720          // wpk  [64] float4           = 256

// ---------------------------------------------------------------------------
// proj_kernel: 160 blocks (round-1 shape: empirically the cheap config),
// 64 rows x 128 cols per block, 256 threads, 4x8 thread tile, transposed-A
// staging for b128 LDS reads. Epilogue: exp2(CSL*x); q rows -> qE row-major
// (pairs are contiguous); k rows -> kET2[b][p][k] as float2 (E_{2p},E_{2p+1})
// so attn loads one coalesced dwordx2 per h-pair.
// ---------------------------------------------------------------------------
__global__ __launch_bounds__(256) void proj_kernel(
    const float* __restrict__ queries, const float* __restrict__ keys,
    const float* __restrict__ Wq, const float* __restrict__ Wk,
    const float* __restrict__ w_v,
    float* __restrict__ qE, float2* __restrict__ kET2, float* __restrict__ wpk)
{
    __shared__ __align__(16) float As[64][68];   // [d][row], pad 68
    __shared__ __align__(16) float Ws[64][128];  // [d][col]

    const int tid = threadIdx.x;
    const int blk = blockIdx.x;
    const bool isQ = blk < 32;                   // 32*64 = 2048 q rows
    const int row0 = isQ ? blk * 64 : (blk - 32) * 64;
    const float* A = isQ ? (queries + row0 * D_) : (keys + row0 * D_);
    const float* W = isQ ? Wq : Wk;

    float acc[4][8];
#pragma unroll
    for (int i = 0; i < 4; i++)
#pragma unroll
        for (int j = 0; j < 8; j++) acc[i][j] = 0.f;

    const int lr  = tid & 63;          // A-stage row
    const int ldb = (tid >> 6) * 16;   // A-stage d base
    const int r4  = (tid >> 4) * 4;    // compute row base 0..60
    const int c8  = (tid & 15) * 8;    // compute col base 0..120

    for (int d0 = 0; d0 < D_; d0 += 64) {
        // stage A transposed: As[d][row]
#pragma unroll
        for (int j = 0; j < 4; j++) {
            const float4 a = *(const float4*)&A[lr * D_ + d0 + ldb + j * 4];
            As[ldb + j * 4 + 0][lr] = a.x;
            As[ldb + j * 4 + 1][lr] = a.y;
            As[ldb + j * 4 + 2][lr] = a.z;
            As[ldb + j * 4 + 3][lr] = a.w;
        }
        // stage W: 64 x 128
#pragma unroll
        for (int l = 0; l < 8; l++) {
            const int idx = tid + l * 256;
            const int rr = idx >> 5, cc = (idx & 31) * 4;
            *(float4*)&Ws[rr][cc] = *(const float4*)&W[(d0 + rr) * H_ + cc];
        }
        __syncthreads();
#pragma unroll 4
        for (int d = 0; d < 64; d++) {
            const float4 a4 = *(const float4*)&As[d][r4];
            const float4 w0 = *(const float4*)&Ws[d][c8];
            const float4 w1 = *(const float4*)&Ws[d][c8 + 4];
            const float ar[4] = {a4.x, a4.y, a4.z, a4.w};
#pragma unroll
            for (int i = 0; i < 4; i++) {
                acc[i][0] = fmaf(ar[i], w0.x, acc[i][0]);
                acc[i][1] = fmaf(ar[i], w0.y, acc[i][1]);
                acc[i][2] = fmaf(ar[i], w0.z, acc[i][2]);
                acc[i][3] = fmaf(ar[i], w0.w, acc[i][3]);
                acc[i][4] = fmaf(ar[i], w1.x, acc[i][4]);
                acc[i][5] = fmaf(ar[i], w1.y, acc[i][5]);
                acc[i][6] = fmaf(ar[i], w1.z, acc[i][6]);
                acc[i][7] = fmaf(ar[i], w1.w, acc[i][7]);
            }
        }
        __syncthreads();
    }

#pragma unroll
    for (int i = 0; i < 4; i++) {
        float e[8];
#pragma unroll
        for (int j = 0; j < 8; j++) e[j] = EXP2F(CSL * acc[i][j]);
        const int row = row0 + r4 + i;
        if (isQ) {
            float* dst = qE + row * H_ + c8;
            *(float4*)dst = make_float4(e[0], e[1], e[2], e[3]);
            *(float4*)(dst + 4) = make_float4(e[4], e[5], e[6], e[7]);
        } else {
            const int b = row >> 10, k = row & 1023;   // 64-row tiles never cross b
            float2* dst = kET2 + (size_t)(b * 64 + (c8 >> 1)) * K_ + k;
#pragma unroll
            for (int jj = 0; jj < 4; jj++)
                dst[jj * K_] = make_float2(e[2 * jj], e[2 * jj + 1]);
        }
    }

    if (blk == 0 && tid < 64) {
        const float w1 = -2.0f * L2E * w_v[2 * tid];
        const float w2 = -2.0f * L2E * w_v[2 * tid + 1];
        *(float4*)&wpk[tid * 4] = make_float4(w1, w2, w1 + w2, 0.f);
    }
}

// ---------------------------------------------------------------------------
// attn_kernel: 1024 threads, 1 k per thread, 4 q-rows per block.
// NEW: masked-k skip — threads with tid >= vl skip phase 1 entirely (whole
// waves for full 64-lane groups), AV k-loop clamped to k < vl. Exact: masked
// p-values are 0 either way. kET2 gives one dwordx2 load per h-pair.
// h-pairing: w1/(1+x1)+w2/(1+x2) = [(w1+w2)+w1*x2+w2*x1]/[(1+x1)(1+x2)].
// ---------------------------------------------------------------------------
__global__ __launch_bounds__(1024, 8) void attn_kernel(
    const float* __restrict__ qE,       // [B*Q][H] = e^{2q}
    const float2* __restrict__ kET2,    // [B][64][K] = (e^{2k})-pairs
    const float* __restrict__ values,   // [B][K][DV]
    const int*   __restrict__ valid_lens,
    const float* __restrict__ wpk,      // [64] float4 (w1,w2,w1+w2,0)
    float* __restrict__ out)            // [B][Q][DV]
{
    __shared__ __align__(16) float sc[K_][4];        // 16 KB p-values
    __shared__ __align__(16) float red[16][4][128];  // 32 KB AV reduction
    __shared__ __align__(16) float psum[16][4];
    __shared__ float rl[4];

    const int tid = threadIdx.x;
    const int b  = blockIdx.y;
    const int q0 = blockIdx.x * 4;
    const int vl = valid_lens[b];

    const float* q0p = qE + (b * Q_ + q0) * H_;
    const float* q1p = q0p + H_;
    const float* q2p = q0p + 2 * H_;
    const float* q3p = q0p + 3 * H_;
    const float2* kb2 = kET2 + (size_t)(b * 64) * K_ + tid;

    float2 acc01 = make_float2(0.f, 0.f);
    float2 acc23 = make_float2(0.f, 0.f);

    if (tid < vl) {
#pragma unroll 4
        for (int p = 0; p < 64; p++) {
            const float2 ek = kb2[(size_t)p * K_];
            const float4 wp = *(const float4*)&wpk[p * 4];
            const float2 qa = *(const float2*)&q0p[2 * p];
            const float2 qb = *(const float2*)&q1p[2 * p];
            const float2 qc = *(const float2*)&q2p[2 * p];
            const float2 qd = *(const float2*)&q3p[2 * p];
            {   // q rows 0,1
                float2 x1 = make_float2(qa.x * ek.x, qb.x * ek.x);
                float2 x2 = make_float2(qa.y * ek.y, qb.y * ek.y);
                float2 e1 = make_float2(x1.x + 1.f, x1.y + 1.f);
                float2 d  = make_float2(fmaf(e1.x, x2.x, e1.x), fmaf(e1.y, x2.y, e1.y));
                float2 n  = make_float2(fmaf(wp.y, x1.x, wp.z), fmaf(wp.y, x1.y, wp.z));
                n = make_float2(fmaf(wp.x, x2.x, n.x), fmaf(wp.x, x2.y, n.y));
                acc01.x = fmaf(n.x, RCPF(d.x), acc01.x);
                acc01.y = fmaf(n.y, RCPF(d.y), acc01.y);
            }
            {   // q rows 2,3
                float2 x1 = make_float2(qc.x * ek.x, qd.x * ek.x);
                float2 x2 = make_float2(qc.y * ek.y, qd.y * ek.y);
                float2 e1 = make_float2(x1.x + 1.f, x1.y + 1.f);
                float2 d  = make_float2(fmaf(e1.x, x2.x, e1.x), fmaf(e1.y, x2.y, e1.y));
                float2 n  = make_float2(fmaf(wp.y, x1.x, wp.z), fmaf(wp.y, x1.y, wp.z));
                n = make_float2(fmaf(wp.x, x2.x, n.x), fmaf(wp.x, x2.y, n.y));
                acc23.x = fmaf(n.x, RCPF(d.x), acc23.x);
                acc23.y = fmaf(n.y, RCPF(d.y), acc23.y);
            }
        }
    }

    // ---- exp + mask + row sums (k = tid) ----
    const bool valid = tid < vl;
    float4 pv;
    pv.x = valid ? EXP2F(acc01.x) : 0.f;
    pv.y = valid ? EXP2F(acc01.y) : 0.f;
    pv.z = valid ? EXP2F(acc23.x) : 0.f;
    pv.w = valid ? EXP2F(acc23.y) : 0.f;
    *(float4*)&sc[tid][0] = pv;

    float4 s = pv;
#pragma unroll
    for (int sh = 32; sh > 0; sh >>= 1) {
        s.x += __shfl_xor(s.x, sh);
        s.y += __shfl_xor(s.y, sh);
        s.z += __shfl_xor(s.z, sh);
        s.w += __shfl_xor(s.w, sh);
    }
    const int lane = tid & 63, w = tid >> 6;
    if (lane == 0) *(float4*)&psum[w][0] = s;
    __syncthreads();
    if (tid < 4) {
        float t = 0.f;
#pragma unroll
        for (int ww = 0; ww < 16; ww++) t += psum[ww][tid];
        rl[tid] = RCPF(t);
    }

    // ---- AV: thread = (kc 0..15, kh 0..1, vg 0..31), k-loop clamped to vl ----
    const int vg = (tid & 31) * 4;
    const int kh = (tid >> 5) & 1;
    const int kc = tid >> 6;
    const float* vb = values + (size_t)b * (K_ * DV_) + vg;
    float av[4][4];
#pragma unroll
    for (int q = 0; q < 4; q++)
#pragma unroll
        for (int j = 0; j < 4; j++) av[q][j] = 0.f;

    const int rem = vl - kc * 64 - kh;
    const int imax = rem <= 0 ? 0 : (((rem + 1) >> 1) > 32 ? 32 : ((rem + 1) >> 1));
#pragma unroll 2
    for (int i = 0; i < imax; i++) {
        const int k = kc * 64 + i * 2 + kh;
        const float4 vv = *(const float4*)&vb[k * DV_];
        const float4 p = *(const float4*)&sc[k][0];
        av[0][0] = fmaf(p.x, vv.x, av[0][0]); av[0][1] = fmaf(p.x, vv.y, av[0][1]);
        av[0][2] = fmaf(p.x, vv.z, av[0][2]); av[0][3] = fmaf(p.x, vv.w, av[0][3]);
        av[1][0] = fmaf(p.y, vv.x, av[1][0]); av[1][1] = fmaf(p.y, vv.y, av[1][1]);
        av[1][2] = fmaf(p.y, vv.z, av[1][2]); av[1][3] = fmaf(p.y, vv.w, av[1][3]);
        av[2][0] = fmaf(p.z, vv.x, av[2][0]); av[2][1] = fmaf(p.z, vv.y, av[2][1]);
        av[2][2] = fmaf(p.z, vv.z, av[2][2]); av[2][3] = fmaf(p.z, vv.w, av[2][3]);
        av[3][0] = fmaf(p.w, vv.x, av[3][0]); av[3][1] = fmaf(p.w, vv.y, av[3][1]);
        av[3][2] = fmaf(p.w, vv.z, av[3][2]); av[3][3] = fmaf(p.w, vv.w, av[3][3]);
    }
    // fold kh pairs (threads tid and tid^32 hold same (kc,vg))
#pragma unroll
    for (int q = 0; q < 4; q++)
#pragma unroll
        for (int j = 0; j < 4; j++) av[q][j] += __shfl_xor(av[q][j], 32);
    if (kh == 0) {
#pragma unroll
        for (int q = 0; q < 4; q++)
            *(float4*)&red[kc][q][vg] = make_float4(av[q][0], av[q][1], av[q][2], av[q][3]);
    }
    __syncthreads();

    if (tid < 512) {
        const int q = tid >> 7, v = tid & 127;
        float t = 0.f;
#pragma unroll
        for (int g = 0; g < 16; g++) t += red[g][q][v];
        out[(b * Q_ + q0 + q) * DV_ + v] = t * rl[q];
    }
}

extern "C" void kernel_launch(void* const* d_in, const int* in_sizes, int n_in,
                              void* d_out, int out_size, void* d_ws, size_t ws_size,
                              hipStream_t stream) {
    const float* queries    = (const float*)d_in[0];  // [8,256,256]
    const float* keys       = (const float*)d_in[1];  // [8,1024,256]
    const float* values     = (const float*)d_in[2];  // [8,1024,128]
    const int*   valid_lens = (const int*)d_in[3];    // [8]
    const float* W_q        = (const float*)d_in[4];  // [256,128]
    const float* W_k        = (const float*)d_in[5];  // [256,128]
    const float* w_v        = (const float*)d_in[6];  // [128]
    float* out = (float*)d_out;

    float*  ws   = (float*)d_ws;
    float*  qE   = ws + QE_OFF;
    float2* kET2 = (float2*)(ws + KE_OFF);
    float*  wpk  = ws + WPK_OFF;

    proj_kernel<<<160, 256, 0, stream>>>(queries, keys, W_q, W_k, w_v, qE, kET2, wpk);
    attn_kernel<<<dim3(Q_ / 4, B_), 1024, 0, stream>>>(qE, kET2, values, valid_lens, wpk, out);
}